// Round 1
// 666.934 us; speedup vs baseline: 1.1354x; 1.1354x over previous
//
#include <hip/hip_runtime.h>
#include <math.h>

// Problem constants: B=4, Nq=2048, Nf=16384, D=3, C=768
#define Bt  4
#define NQ  2048
#define NF  16384
#define CC  768

// ---- old-path (fallback) tile params ----
#define QT  128     // q-rows per main block
#define CT  96      // channels per old main block
#define BK  128     // Nf chunk per LDS stage (old)
#define THR 512     // threads per main block
#define NCH (NF / BK)

// ---- new-path params ----
#define NFS   4                  // Nf splits (partial sums)
#define KC    (NF / NFS)         // 4096 k per block
#define BK2   32                 // k per LDS chunk
#define NCH2  (KC / BK2)         // 128 chunks per block
#define TILEB (CC * BK2 * 2)     // 49152 B per bf16 v-tile (one chunk, all 768 c)
#define NTILE (Bt * (NF / BK2))  // 2048 tiles total

#define SCALE_LOG2E 0.8329080161227079f   // (1/sqrt(3)) * log2(e)

typedef __attribute__((ext_vector_type(8)))  short  short8;
typedef __attribute__((ext_vector_type(4)))  float  floatx4;
typedef __attribute__((ext_vector_type(16))) float  floatx16;

#if __has_builtin(__builtin_amdgcn_exp2f)
#define EXP2F(x) __builtin_amdgcn_exp2f(x)
#else
#define EXP2F(x) __expf((x) * 0.6931471805599453f)
#endif

static __device__ __forceinline__ float relu(float x) { return fmaxf(x, 0.0f); }

// fp32 -> bf16 bits, round-to-nearest-even (inputs finite, non-NaN)
static __device__ __forceinline__ unsigned int f2bf(float f) {
    unsigned int u = __float_as_uint(f);
    u += 0x7fffu + ((u >> 16) & 1u);
    return u >> 16;
}

// direct-to-LDS 16B DMA (linear dest: wave-uniform base + lane*16)
#define GLDS16(gsrc, ldst)                                                        \
    __builtin_amdgcn_global_load_lds(                                             \
        (const __attribute__((address_space(1))) unsigned int*)(gsrc),            \
        (__attribute__((address_space(3))) unsigned int*)(ldst), 16, 0, 0)

// ---------------------------------------------------------------------------
// Kernel 1 (prep): qp = relu(q@W1^T+b1)*SCALE*log2e (float4, w=0 placeholder)
//                  kp = relu(k@W2^T+b2) stored TIGHT float3
// ---------------------------------------------------------------------------
__global__ __launch_bounds__(256) void prep_kernel(
    const float* __restrict__ q, const float* __restrict__ k,
    const float* __restrict__ W1, const float* __restrict__ b1,
    const float* __restrict__ W2, const float* __restrict__ b2,
    float4* __restrict__ qp, float* __restrict__ kp3)
{
    int idx = blockIdx.x * 256 + threadIdx.x;
    if (idx < Bt * NQ) {
        const float* r = q + (size_t)idx * 3;
        float x0 = r[0], x1 = r[1], x2 = r[2];
        float4 o;
        o.x = relu(fmaf(W1[0], x0, fmaf(W1[1], x1, fmaf(W1[2], x2, b1[0])))) * SCALE_LOG2E;
        o.y = relu(fmaf(W1[3], x0, fmaf(W1[4], x1, fmaf(W1[5], x2, b1[1])))) * SCALE_LOG2E;
        o.z = relu(fmaf(W1[6], x0, fmaf(W1[7], x1, fmaf(W1[8], x2, b1[2])))) * SCALE_LOG2E;
        o.w = 0.0f;
        qp[idx] = o;
    } else {
        int kidx = idx - Bt * NQ;   // < Bt*NF by grid construction
        const float* r = k + (size_t)kidx * 3;
        float x0 = r[0], x1 = r[1], x2 = r[2];
        float* dst = kp3 + (size_t)kidx * 3;
        dst[0] = relu(fmaf(W2[0], x0, fmaf(W2[1], x1, fmaf(W2[2], x2, b2[0]))));
        dst[1] = relu(fmaf(W2[3], x0, fmaf(W2[4], x1, fmaf(W2[5], x2, b2[1]))));
        dst[2] = relu(fmaf(W2[6], x0, fmaf(W2[7], x1, fmaf(W2[8], x2, b2[2]))));
    }
}

// ---------------------------------------------------------------------------
// Kernel 2 (stats): rowmax' (log2 domain) and 1/sum(exp2). Writes qp.w = -rm.
// ---------------------------------------------------------------------------
__global__ __launch_bounds__(256) void stats_kernel(
    float4* __restrict__ qp, const float* __restrict__ kp3,
    float2* __restrict__ rstat)
{
    __shared__ float wredA[4][16];
    __shared__ float wredB[4][16];

    const int bid  = blockIdx.x;
    const int b    = bid >> 7;            // NQ/16 = 128 blocks per batch
    const int q0   = (bid & 127) * 16;
    const int t    = threadIdx.x;
    const int wv   = t >> 6;
    const int lane = t & 63;

    float qx[16], qy[16], qz[16];
#pragma unroll
    for (int i = 0; i < 16; ++i) {
        float4 qv = qp[b * NQ + q0 + i];
        qx[i] = qv.x; qy[i] = qv.y; qz[i] = qv.z;
    }
    const float* kpb = kp3 + (size_t)b * NF * 3;

    float pmax[16];
#pragma unroll
    for (int i = 0; i < 16; ++i) pmax[i] = -1e30f;
    for (int m = t; m < NF; m += 256) {
        float kx = kpb[3 * m], ky = kpb[3 * m + 1], kz = kpb[3 * m + 2];
#pragma unroll
        for (int i = 0; i < 16; ++i) {
            float s = fmaf(qx[i], kx, fmaf(qy[i], ky, qz[i] * kz));
            pmax[i] = fmaxf(pmax[i], s);
        }
    }
#pragma unroll
    for (int off = 32; off >= 1; off >>= 1)
#pragma unroll
        for (int i = 0; i < 16; ++i)
            pmax[i] = fmaxf(pmax[i], __shfl_xor(pmax[i], off, 64));
    if (lane == 0)
#pragma unroll
        for (int i = 0; i < 16; ++i) wredA[wv][i] = pmax[i];
    __syncthreads();

    float rowmax[16];
#pragma unroll
    for (int i = 0; i < 16; ++i)
        rowmax[i] = fmaxf(fmaxf(wredA[0][i], wredA[1][i]),
                          fmaxf(wredA[2][i], wredA[3][i]));

    float psum[16];
#pragma unroll
    for (int i = 0; i < 16; ++i) psum[i] = 0.0f;
    for (int m = t; m < NF; m += 256) {
        float kx = kpb[3 * m], ky = kpb[3 * m + 1], kz = kpb[3 * m + 2];
#pragma unroll
        for (int i = 0; i < 16; ++i) {
            float s = fmaf(qx[i], kx, fmaf(qy[i], ky, qz[i] * kz));
            psum[i] += EXP2F(s - rowmax[i]);
        }
    }
#pragma unroll
    for (int off = 32; off >= 1; off >>= 1)
#pragma unroll
        for (int i = 0; i < 16; ++i)
            psum[i] += __shfl_xor(psum[i], off, 64);
    if (lane == 0)
#pragma unroll
        for (int i = 0; i < 16; ++i) wredB[wv][i] = psum[i];
    __syncthreads();

    if (t < 16) {
        float m = fmaxf(fmaxf(wredA[0][t], wredA[1][t]),
                        fmaxf(wredA[2][t], wredA[3][t]));
        float l = wredB[0][t] + wredB[1][t] + wredB[2][t] + wredB[3][t];
        int row = b * NQ + q0 + t;
        rstat[row] = make_float2(m, 1.0f / l);
        qp[row].w = -m;
    }
}

// ---------------------------------------------------------------------------
// Kernel 2b (prep_v): v f32 -> bf16, pre-arranged in the exact swizzled
// B-fragment tile layout so the main kernel can DMA it linearly to LDS.
// Tile (b, ch): byte(c,k) = c*64 + ((k>>3) ^ ((c>>1)&3))*16 + (k&7)*2
// ---------------------------------------------------------------------------
__global__ __launch_bounds__(256) void prep_v_kernel(
    const float* __restrict__ v, char* __restrict__ vpk)
{
    __shared__ float lt[32][68];          // 32 k-rows x 64 c (+4 pad)
    const int t   = threadIdx.x;
    const int bid = blockIdx.x;           // Bt * 512 * 12 blocks
    const int cb  = bid % 12;
    const int ch  = (bid / 12) & 511;
    const int b   = bid / (12 * 512);
    const int c0  = cb * 64;

    // load 32 k x 64 c f32 tile, coalesced
    const float* vb = v + ((size_t)b * NF + (size_t)ch * BK2) * CC + c0;
    const int mi = t >> 4, c4 = (t & 15) << 2;
#pragma unroll
    for (int r2 = 0; r2 < 2; ++r2) {
        const int m = mi + 16 * r2;
        *(float4*)&lt[m][c4] = *(const float4*)(vb + (size_t)m * CC + c4);
    }
    __syncthreads();

    // each thread emits one 16B slot: c = t>>2 (local), logical slot = t&3 (8 k's)
    const int c  = t >> 2;
    const int sl = t & 3;
    unsigned int dw[4];
#pragma unroll
    for (int i = 0; i < 4; ++i) {
        float a  = lt[8 * sl + 2 * i][c];
        float b2 = lt[8 * sl + 2 * i + 1][c];
        asm("v_cvt_pk_bf16_f32 %0, %1, %2" : "=v"(dw[i]) : "v"(a), "v"(b2));
    }
    const int cgl = c0 + c;
    char* dst = vpk + (size_t)(b * 512 + ch) * TILEB
              + ((size_t)cgl << 6) + ((sl ^ ((cgl >> 1) & 3)) << 4);
    uint4 u; u.x = dw[0]; u.y = dw[1]; u.z = dw[2]; u.w = dw[3];
    *(uint4*)dst = u;
}

// ---------------------------------------------------------------------------
// Kernel 3 (main, new): 256 blocks = 4 b x 16 qt x 4 nf-splits.
// Block: 128 q x FULL 768 c x 4096 k. 8 waves = 2 q-groups(64q) x 4 c-groups
// (192c). 32x32x16 MFMA; each wave owns 2 q-subtiles -> every B ds_read_b128
// feeds 2 MFMAs. Scores computed uniform-k from scalar kp loads, then
// redistributed into both A-fragments with cvt_pk_bf16 + permlane32_swap.
// v staged bf16 via global_load_lds (pre-swizzled by prep_v). Writes RAW
// partial sums; reduce_kernel applies 1/l.
// ---------------------------------------------------------------------------
__global__ __launch_bounds__(512) void attn_main32_kernel(
    const char* __restrict__ vpk, const float4* __restrict__ qp,
    const float* __restrict__ kp3, float* __restrict__ out,
    float* __restrict__ partial)
{
    __shared__ __align__(16) char vbuf[2][TILEB];   // 2 x 48 KiB double buffer

    const int t   = threadIdx.x;
    const int l   = t & 63;
    const int wv  = t >> 6;
    const int wg  = wv >> 2;          // q-group 0..1 (64 rows each)
    const int cg  = wv & 3;           // c-group 0..3 (192 cols each)

    const int bid = blockIdx.x;
    // XCD swizzle: the two (b,nfs) groups sharing an XCD keep their v/kp slab in L2
    const int g   = ((bid & 7) << 1) | ((bid >> 3) & 1);  // 0..15 -> (b, nfs)
    const int qt  = bid >> 4;                             // 0..15
    const int b   = g >> 2;
    const int nfs = g & 3;

    const char*  vtile = vpk + (size_t)(b * (NF / BK2) + nfs * NCH2) * TILEB;
    const float* kpb   = kp3 + (size_t)(b * NF + nfs * KC) * 3;

    // lane l owns q-row wg*64 + l. qp.w already = -rowmax (log2 domain).
    const float4 qv = qp[b * NQ + qt * QT + wg * 64 + l];
    const float qx = qv.x, qy = qv.y, qz = qv.z, qw = qv.w;

    floatx16 acc[2][6];
#pragma unroll
    for (int qs = 0; qs < 2; ++qs)
#pragma unroll
        for (int cs = 0; cs < 6; ++cs)
#pragma unroll
            for (int r = 0; r < 16; ++r) acc[qs][cs][r] = 0.0f;

    const int lhi  = l >> 5;
    const int swzl = (l >> 1) & 3;                       // ((c>>1)&3) with c ~ l&31 mod 32
    const int bofs = ((cg * 192 + (l & 31)) << 6);       // c*64; +cs*2048 via imm offset

    // ---- prologue: stage chunk 0 -> buf0 ----
    {
        const char* src = vtile + wv * 1024 + l * 16;
        char* dst = &vbuf[0][wv * 1024];
#pragma unroll
        for (int i = 0; i < 6; ++i) GLDS16(src + i * 8192, dst + i * 8192);
    }

#pragma unroll 1
    for (int ch = 0; ch < NCH2; ++ch) {
        const int p = ch & 1;
        // own DMAs for chunk ch done (they had a full chunk of compute to land)
        asm volatile("s_waitcnt vmcnt(0)" ::: "memory");
        __builtin_amdgcn_sched_barrier(0);
        __builtin_amdgcn_s_barrier();     // everyone's DMAs landed AND prev chunk fully read
        __builtin_amdgcn_sched_barrier(0);
        if (ch + 1 < NCH2) {              // prefetch next chunk into the other buffer
            const char* src = vtile + (size_t)(ch + 1) * TILEB + wv * 1024 + l * 16;
            char* dst = &vbuf[p ^ 1][wv * 1024];
#pragma unroll
            for (int i = 0; i < 6; ++i) GLDS16(src + i * 8192, dst + i * 8192);
        }
        __builtin_amdgcn_sched_barrier(0);

        const char* vbp = &vbuf[p][0];
#pragma unroll
        for (int kk = 0; kk < 2; ++kk) {
            // uniform kp for this K16 step -> scalar loads (1 SGPR per fma is legal)
            const float4* kp4 = (const float4*)(kpb + (size_t)(ch * BK2 + kk * 16) * 3);

            unsigned int d[8];                 // d[j] = bf16 pair (k=2j, 2j+1)
#pragma unroll
            for (int g4 = 0; g4 < 4; ++g4) {   // 4 k's per group, 12 floats live
                const float4 ka = kp4[3 * g4 + 0];
                const float4 kb = kp4[3 * g4 + 1];
                const float4 kc = kp4[3 * g4 + 2];
                float e0, e1;
                e0 = EXP2F(fmaf(qx, ka.x, fmaf(qy, ka.y, fmaf(qz, ka.z, qw))));
                e1 = EXP2F(fmaf(qx, ka.w, fmaf(qy, kb.x, fmaf(qz, kb.y, qw))));
                asm("v_cvt_pk_bf16_f32 %0, %1, %2" : "=v"(d[2 * g4]) : "v"(e0), "v"(e1));
                e0 = EXP2F(fmaf(qx, kb.z, fmaf(qy, kb.w, fmaf(qz, kc.x, qw))));
                e1 = EXP2F(fmaf(qx, kc.y, fmaf(qy, kc.z, fmaf(qz, kc.w, qw))));
                asm("v_cvt_pk_bf16_f32 %0, %1, %2" : "=v"(d[2 * g4 + 1]) : "v"(e0), "v"(e1));
            }
            // redistribute: after swap, d[0..3] = A-frag of q-sub 0, d[4..7] = q-sub 1
#pragma unroll
            for (int jj = 0; jj < 4; ++jj)
                asm("v_permlane32_swap_b32 %0, %1" : "+v"(d[jj]), "+v"(d[jj + 4]));

            union { unsigned int u[4]; short8 s; } a0, a1;
#pragma unroll
            for (int jj = 0; jj < 4; ++jj) { a0.u[jj] = d[jj]; a1.u[jj] = d[jj + 4]; }

            const int swz  = ((2 * kk + lhi) ^ swzl) << 4;
            const char* bp = vbp + bofs + swz;

            __builtin_amdgcn_s_setprio(1);
#pragma unroll
            for (int cs = 0; cs < 6; ++cs) {
                union { uint4 u; short8 s; } bw;
                bw.u = *(const uint4*)(bp + cs * 2048);
                acc[0][cs] = __builtin_amdgcn_mfma_f32_32x32x16_bf16(a0.s, bw.s, acc[0][cs], 0, 0, 0);
                acc[1][cs] = __builtin_amdgcn_mfma_f32_32x32x16_bf16(a1.s, bw.s, acc[1][cs], 0, 0, 0);
            }
            __builtin_amdgcn_s_setprio(0);
        }
    }

    // ---- epilogue: raw partial sums (split 0 -> out, splits 1..3 -> ws) ----
    float* obase = (nfs == 0) ? out
                 : (partial + (size_t)(nfs - 1) * ((size_t)Bt * NQ * CC));
    const int row0 = b * NQ + qt * QT + wg * 64 + 4 * lhi;
    const int col0 = cg * 192 + (l & 31);
#pragma unroll
    for (int qs = 0; qs < 2; ++qs)
#pragma unroll
        for (int cs = 0; cs < 6; ++cs)
#pragma unroll
            for (int r = 0; r < 16; ++r) {
                const int row = row0 + qs * 32 + (r & 3) + 8 * (r >> 2);
                obase[(size_t)row * CC + col0 + cs * 32] = acc[qs][cs][r];
            }
}

// ---------------------------------------------------------------------------
// Kernel 4 (reduce): out = (out + p1 + p2 + p3) * (1/l)
// ---------------------------------------------------------------------------
__global__ __launch_bounds__(256) void reduce_kernel(
    float* __restrict__ out, const float* __restrict__ part,
    const float2* __restrict__ rstat)
{
    const int TOT4 = Bt * NQ * CC / 4;     // 1,572,864
    float4* o4 = (float4*)out;
    const float4* p4 = (const float4*)part;
    for (int i = blockIdx.x * 256 + threadIdx.x; i < TOT4; i += gridDim.x * 256) {
        float4 o = o4[i];
        float4 a = p4[i], b2 = p4[TOT4 + i], c2 = p4[2 * TOT4 + i];
        float lv = rstat[i / (CC / 4)].y;
        o.x = (o.x + a.x + b2.x + c2.x) * lv;
        o.y = (o.y + a.y + b2.y + c2.y) * lv;
        o.z = (o.z + a.z + b2.z + c2.z) * lv;
        o.w = (o.w + a.w + b2.w + c2.w) * lv;
        o4[i] = o;
    }
}

// ---------------------------------------------------------------------------
// FALLBACK (old main kernel, known-good): used only if ws_size is too small
// for the bf16 v-prepack + partial buffers.
// ---------------------------------------------------------------------------
__global__ __launch_bounds__(THR, 4) void attn_mfma_kernel(
    const float* __restrict__ v, const float4* __restrict__ qp,
    const float* __restrict__ kp3, const float2* __restrict__ rstat,
    float* __restrict__ out)
{
    __shared__ unsigned int vTd[2][CT * 68];
    __shared__ float4 kplB[2][96];

    const int t    = threadIdx.x;
    const int bid  = blockIdx.x;
    const int g    = (bid & 7) + 8 * ((bid >> 3) & 3);
    const int qt   = bid >> 5;
    const int b    = g >> 3;
    const int ct   = g & 7;

    const int lane = t & 63;
    const int wv   = t >> 6;
    const int quad = lane >> 4;
    const int l15  = lane & 15;

    const int qrow0 = b * NQ + qt * QT;
    const int cbase = ct * CT;

    float4 qv = qp[qrow0 + wv * 16 + l15];
    const float qx = qv.x, qy = qv.y, qz = qv.z, qw = qv.w;

    const int rp  = (t & 7) + 8 * wv;
    const int c4l = (t >> 3) & 7;

    const float*  vb   = v + (size_t)b * NF * CC + cbase;
    const float4* kp4g = (const float4*)(kp3 + (size_t)b * NF * 3);

    floatx4 acc[6];
#pragma unroll
    for (int cs = 0; cs < 6; ++cs) acc[cs] = (floatx4){0.f, 0.f, 0.f, 0.f};

    float va0[3][4], va1[3][4];
    float4 kpld = make_float4(0.f, 0.f, 0.f, 0.f);

#pragma unroll
    for (int rep = 0; rep < 3; ++rep) {
        int col = 4 * (c4l + 8 * rep);
        const float4* p0 = (const float4*)(vb + (size_t)(2 * rp) * CC + col);
        float4 a = p0[0];
        float4 bq = p0[CC / 4];
        va0[rep][0] = a.x;  va0[rep][1] = a.y;  va0[rep][2] = a.z;  va0[rep][3] = a.w;
        va1[rep][0] = bq.x; va1[rep][1] = bq.y; va1[rep][2] = bq.z; va1[rep][3] = bq.w;
    }
    if (t < 96) kpld = kp4g[t];

    for (int ch = 0; ch < NCH; ++ch) {
        const int p = ch & 1;
#pragma unroll
        for (int rep = 0; rep < 3; ++rep) {
            int c0 = 4 * (c4l + 8 * rep);
#pragma unroll
            for (int w = 0; w < 4; ++w) {
                unsigned int pk = f2bf(va0[rep][w]) | (f2bf(va1[rep][w]) << 16);
                vTd[p][(c0 + w) * 68 + (rp ^ (4 * c4l))] = pk;
            }
        }
        if (t < 96) kplB[p][t] = kpld;
        __syncthreads();

        if (ch + 1 < NCH) {
            int m0 = (ch + 1) * BK;
#pragma unroll
            for (int rep = 0; rep < 3; ++rep) {
                int col = 4 * (c4l + 8 * rep);
                const float4* p0 = (const float4*)(vb + (size_t)(m0 + 2 * rp) * CC + col);
                float4 a = p0[0];
                float4 bq = p0[CC / 4];
                va0[rep][0] = a.x;  va0[rep][1] = a.y;  va0[rep][2] = a.z;  va0[rep][3] = a.w;
                va1[rep][0] = bq.x; va1[rep][1] = bq.y; va1[rep][2] = bq.z; va1[rep][3] = bq.w;
            }
            if (t < 96) kpld = kp4g[(ch + 1) * 96 + t];
        }

#pragma unroll
        for (int kk = 0; kk < BK; kk += 32) {
            union { float4 v4[6]; float f[24]; } kq;
            const int kb4 = (kk * 3) / 4 + 6 * quad;
#pragma unroll
            for (int i = 0; i < 6; ++i) kq.v4[i] = kplB[p][kb4 + i];

            union { short8 s; unsigned int d[4]; } af;
#pragma unroll
            for (int j = 0; j < 8; j += 2) {
                float s0 = fmaf(qx, kq.f[3 * j],
                           fmaf(qy, kq.f[3 * j + 1],
                           fmaf(qz, kq.f[3 * j + 2], qw)));
                float s1 = fmaf(qx, kq.f[3 * j + 3],
                           fmaf(qy, kq.f[3 * j + 4],
                           fmaf(qz, kq.f[3 * j + 5], qw)));
                af.d[j >> 1] = f2bf(EXP2F(s0)) | (f2bf(EXP2F(s1)) << 16);
            }

#pragma unroll
            for (int cs = 0; cs < 6; ++cs) {
                int c  = cs * 16 + l15;
                int d0 = ((kk >> 1) + 4 * quad) ^ (4 * ((c >> 2) & 7));
                union { uint4 u; short8 s; } bw;
                bw.u = *(const uint4*)&vTd[p][c * 68 + d0];
                acc[cs] = __builtin_amdgcn_mfma_f32_16x16x32_bf16(
                    af.s, bw.s, acc[cs], 0, 0, 0);
            }
        }
        __syncthreads();
    }

#pragma unroll
    for (int vv = 0; vv < 4; ++vv) {
        int row = qrow0 + wv * 16 + quad * 4 + vv;
        float lv = rstat[row].y;
        float* orow = out + (size_t)row * CC + cbase + l15;
#pragma unroll
        for (int cs = 0; cs < 6; ++cs)
            orow[cs * 16] = acc[cs][vv] * lv;
    }
}

// ---------------------------------------------------------------------------
extern "C" void kernel_launch(void* const* d_in, const int* in_sizes, int n_in,
                              void* d_out, int out_size, void* d_ws, size_t ws_size,
                              hipStream_t stream) {
    const float* q  = (const float*)d_in[0];
    const float* k  = (const float*)d_in[1];
    const float* v  = (const float*)d_in[2];
    const float* W1 = (const float*)d_in[3];
    const float* b1 = (const float*)d_in[4];
    const float* W2 = (const float*)d_in[5];
    const float* b2 = (const float*)d_in[6];
    float* out = (float*)d_out;

    // ws layout: kp3 (768K) | qp (128K) | rstat (64K) | vpk (96M) | partials (72M)
    float*  kp3   = (float*)d_ws;
    float4* qpW   = (float4*)((char*)d_ws + (size_t)Bt * NF * 3 * 4);
    float2* rstat = (float2*)((char*)d_ws + (size_t)Bt * NF * 3 * 4 + (size_t)Bt * NQ * 16);
    char*   vpk   = (char*)d_ws + 983040;
    float*  part  = (float*)((char*)d_ws + 983040 + (size_t)NTILE * TILEB);
    const size_t need = 983040 + (size_t)NTILE * TILEB
                      + (size_t)3 * Bt * NQ * CC * 4;   // ~177.1 MB

    hipLaunchKernelGGL(prep_kernel, dim3((Bt * NQ + Bt * NF) / 256), dim3(256), 0, stream,
                       q, k, W1, b1, W2, b2, qpW, kp3);
    hipLaunchKernelGGL(stats_kernel, dim3(Bt * (NQ / 16)), dim3(256), 0, stream,
                       qpW, kp3, rstat);

    if (ws_size >= need) {
        hipLaunchKernelGGL(prep_v_kernel, dim3(Bt * 512 * 12), dim3(256), 0, stream,
                           v, vpk);
        hipLaunchKernelGGL(attn_main32_kernel, dim3(256), dim3(512), 0, stream,
                           vpk, qpW, kp3, out, part);
        hipLaunchKernelGGL(reduce_kernel, dim3(2048), dim3(256), 0, stream,
                           out, part, rstat);
    } else {
        // workspace too small for prepack+partials: proven fallback path
        hipLaunchKernelGGL(attn_mfma_kernel, dim3(Bt * (NQ / QT) * (CC / CT)), dim3(THR), 0, stream,
                           v, qpW, kp3, rstat, out);
    }
}

// Round 2
// 656.565 us; speedup vs baseline: 1.1534x; 1.0158x over previous
//
#include <hip/hip_runtime.h>
#include <math.h>

// Problem constants: B=4, Nq=2048, Nf=16384, D=3, C=768
#define Bt  4
#define NQ  2048
#define NF  16384
#define CC  768

// ---- old-path (fallback) tile params ----
#define QT  128     // q-rows per main block
#define CT  96      // channels per old main block
#define BK  128     // Nf chunk per LDS stage (old)
#define THR 512     // threads per main block
#define NCH (NF / BK)

// ---- new-path params ----
#define NFS   4                  // Nf splits (partial sums)
#define KC    (NF / NFS)         // 4096 k per block
#define BK2   32                 // k per LDS chunk
#define NCH2  (KC / BK2)         // 128 chunks per block
#define TILEB (CC * BK2 * 2)     // 49152 B per bf16 v-tile (one chunk, all 768 c)
#define NTILE (Bt * (NF / BK2))  // 2048 tiles total
#define NBUF  3                  // LDS buffers (depth-2 prefetch, counted vmcnt)

#define SCALE_LOG2E 0.8329080161227079f   // (1/sqrt(3)) * log2(e)

typedef __attribute__((ext_vector_type(8)))  short  short8;
typedef __attribute__((ext_vector_type(4)))  float  floatx4;
typedef __attribute__((ext_vector_type(16))) float  floatx16;

#if __has_builtin(__builtin_amdgcn_exp2f)
#define EXP2F(x) __builtin_amdgcn_exp2f(x)
#else
#define EXP2F(x) __expf((x) * 0.6931471805599453f)
#endif

static __device__ __forceinline__ float relu(float x) { return fmaxf(x, 0.0f); }

// fp32 -> bf16 bits, round-to-nearest-even (inputs finite, non-NaN)
static __device__ __forceinline__ unsigned int f2bf(float f) {
    unsigned int u = __float_as_uint(f);
    u += 0x7fffu + ((u >> 16) & 1u);
    return u >> 16;
}

// direct-to-LDS 16B DMA (linear dest: wave-uniform base + lane*16)
#define GLDS16(gsrc, ldst)                                                        \
    __builtin_amdgcn_global_load_lds(                                             \
        (const __attribute__((address_space(1))) unsigned int*)(gsrc),            \
        (__attribute__((address_space(3))) unsigned int*)(ldst), 16, 0, 0)

// ---------------------------------------------------------------------------
// Kernel 1 (prep): qp = relu(q@W1^T+b1)*SCALE*log2e (float4, w=0 placeholder)
//                  kp = relu(k@W2^T+b2) stored TIGHT float3
// ---------------------------------------------------------------------------
__global__ __launch_bounds__(256) void prep_kernel(
    const float* __restrict__ q, const float* __restrict__ k,
    const float* __restrict__ W1, const float* __restrict__ b1,
    const float* __restrict__ W2, const float* __restrict__ b2,
    float4* __restrict__ qp, float* __restrict__ kp3)
{
    int idx = blockIdx.x * 256 + threadIdx.x;
    if (idx < Bt * NQ) {
        const float* r = q + (size_t)idx * 3;
        float x0 = r[0], x1 = r[1], x2 = r[2];
        float4 o;
        o.x = relu(fmaf(W1[0], x0, fmaf(W1[1], x1, fmaf(W1[2], x2, b1[0])))) * SCALE_LOG2E;
        o.y = relu(fmaf(W1[3], x0, fmaf(W1[4], x1, fmaf(W1[5], x2, b1[1])))) * SCALE_LOG2E;
        o.z = relu(fmaf(W1[6], x0, fmaf(W1[7], x1, fmaf(W1[8], x2, b1[2])))) * SCALE_LOG2E;
        o.w = 0.0f;
        qp[idx] = o;
    } else {
        int kidx = idx - Bt * NQ;   // < Bt*NF by grid construction
        const float* r = k + (size_t)kidx * 3;
        float x0 = r[0], x1 = r[1], x2 = r[2];
        float* dst = kp3 + (size_t)kidx * 3;
        dst[0] = relu(fmaf(W2[0], x0, fmaf(W2[1], x1, fmaf(W2[2], x2, b2[0]))));
        dst[1] = relu(fmaf(W2[3], x0, fmaf(W2[4], x1, fmaf(W2[5], x2, b2[1]))));
        dst[2] = relu(fmaf(W2[6], x0, fmaf(W2[7], x1, fmaf(W2[8], x2, b2[2]))));
    }
}

// ---------------------------------------------------------------------------
// Kernel 2 (stats): rowmax' (log2 domain) and 1/sum(exp2). Writes qp.w = -rm.
// ---------------------------------------------------------------------------
__global__ __launch_bounds__(256) void stats_kernel(
    float4* __restrict__ qp, const float* __restrict__ kp3,
    float2* __restrict__ rstat)
{
    __shared__ float wredA[4][16];
    __shared__ float wredB[4][16];

    const int bid  = blockIdx.x;
    const int b    = bid >> 7;            // NQ/16 = 128 blocks per batch
    const int q0   = (bid & 127) * 16;
    const int t    = threadIdx.x;
    const int wv   = t >> 6;
    const int lane = t & 63;

    float qx[16], qy[16], qz[16];
#pragma unroll
    for (int i = 0; i < 16; ++i) {
        float4 qv = qp[b * NQ + q0 + i];
        qx[i] = qv.x; qy[i] = qv.y; qz[i] = qv.z;
    }
    const float* kpb = kp3 + (size_t)b * NF * 3;

    float pmax[16];
#pragma unroll
    for (int i = 0; i < 16; ++i) pmax[i] = -1e30f;
    for (int m = t; m < NF; m += 256) {
        float kx = kpb[3 * m], ky = kpb[3 * m + 1], kz = kpb[3 * m + 2];
#pragma unroll
        for (int i = 0; i < 16; ++i) {
            float s = fmaf(qx[i], kx, fmaf(qy[i], ky, qz[i] * kz));
            pmax[i] = fmaxf(pmax[i], s);
        }
    }
#pragma unroll
    for (int off = 32; off >= 1; off >>= 1)
#pragma unroll
        for (int i = 0; i < 16; ++i)
            pmax[i] = fmaxf(pmax[i], __shfl_xor(pmax[i], off, 64));
    if (lane == 0)
#pragma unroll
        for (int i = 0; i < 16; ++i) wredA[wv][i] = pmax[i];
    __syncthreads();

    float rowmax[16];
#pragma unroll
    for (int i = 0; i < 16; ++i)
        rowmax[i] = fmaxf(fmaxf(wredA[0][i], wredA[1][i]),
                          fmaxf(wredA[2][i], wredA[3][i]));

    float psum[16];
#pragma unroll
    for (int i = 0; i < 16; ++i) psum[i] = 0.0f;
    for (int m = t; m < NF; m += 256) {
        float kx = kpb[3 * m], ky = kpb[3 * m + 1], kz = kpb[3 * m + 2];
#pragma unroll
        for (int i = 0; i < 16; ++i) {
            float s = fmaf(qx[i], kx, fmaf(qy[i], ky, qz[i] * kz));
            psum[i] += EXP2F(s - rowmax[i]);
        }
    }
#pragma unroll
    for (int off = 32; off >= 1; off >>= 1)
#pragma unroll
        for (int i = 0; i < 16; ++i)
            psum[i] += __shfl_xor(psum[i], off, 64);
    if (lane == 0)
#pragma unroll
        for (int i = 0; i < 16; ++i) wredB[wv][i] = psum[i];
    __syncthreads();

    if (t < 16) {
        float m = fmaxf(fmaxf(wredA[0][t], wredA[1][t]),
                        fmaxf(wredA[2][t], wredA[3][t]));
        float l = wredB[0][t] + wredB[1][t] + wredB[2][t] + wredB[3][t];
        int row = b * NQ + q0 + t;
        rstat[row] = make_float2(m, 1.0f / l);
        qp[row].w = -m;
    }
}

// ---------------------------------------------------------------------------
// Kernel 2b (prep_v): v f32 -> bf16, pre-arranged in the exact swizzled
// B-fragment tile layout so the main kernel can DMA it linearly to LDS.
// Tile (b, ch): byte(c,k) = c*64 + slot*16 + (k&7)*2,
//   slot = (k>>3) ^ (((c>>1) ^ (c>>3)) & 3)      <- c>>3 term kills the
// period-8 bank collision (c, c+8, c+16, c+24 now map to distinct slots).
// ---------------------------------------------------------------------------
__global__ __launch_bounds__(256) void prep_v_kernel(
    const float* __restrict__ v, char* __restrict__ vpk)
{
    __shared__ float lt[32][68];          // 32 k-rows x 64 c (+4 pad)
    const int t   = threadIdx.x;
    const int bid = blockIdx.x;           // Bt * 512 * 12 blocks
    const int cb  = bid % 12;
    const int ch  = (bid / 12) & 511;
    const int b   = bid / (12 * 512);
    const int c0  = cb * 64;

    // load 32 k x 64 c f32 tile, coalesced
    const float* vb = v + ((size_t)b * NF + (size_t)ch * BK2) * CC + c0;
    const int mi = t >> 4, c4 = (t & 15) << 2;
#pragma unroll
    for (int r2 = 0; r2 < 2; ++r2) {
        const int m = mi + 16 * r2;
        *(float4*)&lt[m][c4] = *(const float4*)(vb + (size_t)m * CC + c4);
    }
    __syncthreads();

    // each thread emits one 16B slot: c = t>>2 (local), logical slot = t&3 (8 k's)
    const int c  = t >> 2;
    const int sl = t & 3;
    unsigned int dw[4];
#pragma unroll
    for (int i = 0; i < 4; ++i) {
        float a  = lt[8 * sl + 2 * i][c];
        float b2 = lt[8 * sl + 2 * i + 1][c];
        asm("v_cvt_pk_bf16_f32 %0, %1, %2" : "=v"(dw[i]) : "v"(a), "v"(b2));
    }
    const int cgl = c0 + c;
    char* dst = vpk + (size_t)(b * 512 + ch) * TILEB
              + ((size_t)cgl << 6)
              + ((sl ^ (((cgl >> 1) ^ (cgl >> 3)) & 3)) << 4);
    uint4 u; u.x = dw[0]; u.y = dw[1]; u.z = dw[2]; u.w = dw[3];
    *(uint4*)dst = u;
}

// ---------------------------------------------------------------------------
// Kernel 3 (main, new): 256 blocks = 4 b x 16 qt x 4 nf-splits.
// Block: 128 q x FULL 768 c x 4096 k. 8 waves = 2 q-groups(64q) x 4 c-groups.
// 32x32x16 MFMA; each wave owns 2 q-subtiles -> every B ds_read_b128 feeds
// 2 MFMAs. kp via uniform SMEM loads (lgkmcnt -> counted vmcnt is safe).
// NEW: 3-buffer LDS pipeline, depth-2 prefetch, s_waitcnt vmcnt(6) per chunk
// (never drains the in-flight prefetches); vmcnt(0) only on the last chunk.
// ---------------------------------------------------------------------------
__global__ __launch_bounds__(512) void attn_main32_kernel(
    const char* __restrict__ vpk, const float4* __restrict__ qp,
    const float* __restrict__ kp3, float* __restrict__ out,
    float* __restrict__ partial)
{
    __shared__ __align__(16) char vbuf[NBUF][TILEB];   // 3 x 48 KiB

    const int t   = threadIdx.x;
    const int l   = t & 63;
    const int wv  = t >> 6;
    const int wg  = wv >> 2;          // q-group 0..1 (64 rows each)
    const int cg  = wv & 3;           // c-group 0..3 (192 cols each)

    const int bid = blockIdx.x;
    // XCD swizzle: all 16 qt-blocks of one (b,nfs) share an XCD -> v/kp in L2
    const int g   = ((bid & 7) << 1) | ((bid >> 3) & 1);  // 0..15 -> (b, nfs)
    const int qt  = bid >> 4;                             // 0..15
    const int b   = g >> 2;
    const int nfs = g & 3;

    const char*  vtile = vpk + (size_t)(b * (NF / BK2) + nfs * NCH2) * TILEB;
    const float* kpb   = kp3 + (size_t)(b * NF + nfs * KC) * 3;

    // lane l owns q-row wg*64 + l. qp.w already = -rowmax (log2 domain).
    const float4 qv = qp[b * NQ + qt * QT + wg * 64 + l];
    const float qx = qv.x, qy = qv.y, qz = qv.z, qw = qv.w;

    floatx16 acc[2][6];
#pragma unroll
    for (int qs = 0; qs < 2; ++qs)
#pragma unroll
        for (int cs = 0; cs < 6; ++cs)
#pragma unroll
            for (int r = 0; r < 16; ++r) acc[qs][cs][r] = 0.0f;

    const int lhi  = l >> 5;
    const int swzl = ((l >> 1) ^ (l >> 3)) & 3;          // matches prep_v slot XOR
    const int bofs = ((cg * 192 + (l & 31)) << 6);       // c*64; +cs*2048 via imm

    // ---- prologue: stage chunks 0,1 -> buf0,buf1 (12 loads in flight) ----
#pragma unroll
    for (int pc = 0; pc < 2; ++pc) {
        const char* src = vtile + (size_t)pc * TILEB + wv * 1024 + l * 16;
        char* dst = &vbuf[pc][wv * 1024];
#pragma unroll
        for (int i = 0; i < 6; ++i) GLDS16(src + i * 8192, dst + i * 8192);
    }

    int p = 0;
#pragma unroll 1
    for (int ch = 0; ch < NCH2; ++ch) {
        // counted wait: newest 6 = chunk ch+1's DMAs stay in flight
        if (ch < NCH2 - 1) asm volatile("s_waitcnt vmcnt(6)" ::: "memory");
        else               asm volatile("s_waitcnt vmcnt(0)" ::: "memory");
        __builtin_amdgcn_sched_barrier(0);
        __builtin_amdgcn_s_barrier();     // all waves' DMA(ch) landed; buf[(ch+2)%3] free
        __builtin_amdgcn_sched_barrier(0);
        if (ch + 2 < NCH2) {              // depth-2 prefetch into the free buffer
            const int pn = (p + 2 >= NBUF) ? p + 2 - NBUF : p + 2;
            const char* src = vtile + (size_t)(ch + 2) * TILEB + wv * 1024 + l * 16;
            char* dst = &vbuf[pn][wv * 1024];
#pragma unroll
            for (int i = 0; i < 6; ++i) GLDS16(src + i * 8192, dst + i * 8192);
        }
        __builtin_amdgcn_sched_barrier(0);

        const char* vbp = &vbuf[p][0];
#pragma unroll
        for (int kk = 0; kk < 2; ++kk) {
            // uniform kp for this K16 step -> SMEM loads (1 SGPR per fma is legal)
            const float4* kp4 = (const float4*)(kpb + (size_t)(ch * BK2 + kk * 16) * 3);

            unsigned int d[8];                 // d[j] = bf16 pair (k=2j, 2j+1)
#pragma unroll
            for (int g4 = 0; g4 < 4; ++g4) {   // 4 k's per group, 12 floats live
                const float4 ka = kp4[3 * g4 + 0];
                const float4 kb = kp4[3 * g4 + 1];
                const float4 kc = kp4[3 * g4 + 2];
                float e0, e1;
                e0 = EXP2F(fmaf(qx, ka.x, fmaf(qy, ka.y, fmaf(qz, ka.z, qw))));
                e1 = EXP2F(fmaf(qx, ka.w, fmaf(qy, kb.x, fmaf(qz, kb.y, qw))));
                asm("v_cvt_pk_bf16_f32 %0, %1, %2" : "=v"(d[2 * g4]) : "v"(e0), "v"(e1));
                e0 = EXP2F(fmaf(qx, kb.z, fmaf(qy, kb.w, fmaf(qz, kc.x, qw))));
                e1 = EXP2F(fmaf(qx, kc.y, fmaf(qy, kc.z, fmaf(qz, kc.w, qw))));
                asm("v_cvt_pk_bf16_f32 %0, %1, %2" : "=v"(d[2 * g4 + 1]) : "v"(e0), "v"(e1));
            }
            // redistribute: after swap, d[0..3] = A-frag of q-sub 0, d[4..7] = q-sub 1
#pragma unroll
            for (int jj = 0; jj < 4; ++jj)
                asm("v_permlane32_swap_b32 %0, %1" : "+v"(d[jj]), "+v"(d[jj + 4]));

            union { unsigned int u[4]; short8 s; } a0, a1;
#pragma unroll
            for (int jj = 0; jj < 4; ++jj) { a0.u[jj] = d[jj]; a1.u[jj] = d[jj + 4]; }

            const int swz  = ((2 * kk + lhi) ^ swzl) << 4;
            const char* bp = vbp + bofs + swz;

            __builtin_amdgcn_s_setprio(1);
#pragma unroll
            for (int cs = 0; cs < 6; ++cs) {
                union { uint4 u; short8 s; } bw;
                bw.u = *(const uint4*)(bp + cs * 2048);
                acc[0][cs] = __builtin_amdgcn_mfma_f32_32x32x16_bf16(a0.s, bw.s, acc[0][cs], 0, 0, 0);
                acc[1][cs] = __builtin_amdgcn_mfma_f32_32x32x16_bf16(a1.s, bw.s, acc[1][cs], 0, 0, 0);
            }
            __builtin_amdgcn_s_setprio(0);
        }
        p = (p + 1 == NBUF) ? 0 : p + 1;
    }

    // ---- epilogue: raw partial sums (split 0 -> out, splits 1..3 -> ws) ----
    float* obase = (nfs == 0) ? out
                 : (partial + (size_t)(nfs - 1) * ((size_t)Bt * NQ * CC));
    const int row0 = b * NQ + qt * QT + wg * 64 + 4 * lhi;
    const int col0 = cg * 192 + (l & 31);
#pragma unroll
    for (int qs = 0; qs < 2; ++qs)
#pragma unroll
        for (int cs = 0; cs < 6; ++cs)
#pragma unroll
            for (int r = 0; r < 16; ++r) {
                const int row = row0 + qs * 32 + (r & 3) + 8 * (r >> 2);
                obase[(size_t)row * CC + col0 + cs * 32] = acc[qs][cs][r];
            }
}

// ---------------------------------------------------------------------------
// Kernel 4 (reduce): out = (out + p1 + p2 + p3) * (1/l)
// ---------------------------------------------------------------------------
__global__ __launch_bounds__(256) void reduce_kernel(
    float* __restrict__ out, const float* __restrict__ part,
    const float2* __restrict__ rstat)
{
    const int TOT4 = Bt * NQ * CC / 4;     // 1,572,864
    float4* o4 = (float4*)out;
    const float4* p4 = (const float4*)part;
    for (int i = blockIdx.x * 256 + threadIdx.x; i < TOT4; i += gridDim.x * 256) {
        float4 o = o4[i];
        float4 a = p4[i], b2 = p4[TOT4 + i], c2 = p4[2 * TOT4 + i];
        float lv = rstat[i / (CC / 4)].y;
        o.x = (o.x + a.x + b2.x + c2.x) * lv;
        o.y = (o.y + a.y + b2.y + c2.y) * lv;
        o.z = (o.z + a.z + b2.z + c2.z) * lv;
        o.w = (o.w + a.w + b2.w + c2.w) * lv;
        o4[i] = o;
    }
}

// ---------------------------------------------------------------------------
// FALLBACK (old main kernel, known-good): used only if ws_size is too small
// for the bf16 v-prepack + partial buffers.
// ---------------------------------------------------------------------------
__global__ __launch_bounds__(THR, 4) void attn_mfma_kernel(
    const float* __restrict__ v, const float4* __restrict__ qp,
    const float* __restrict__ kp3, const float2* __restrict__ rstat,
    float* __restrict__ out)
{
    __shared__ unsigned int vTd[2][CT * 68];
    __shared__ float4 kplB[2][96];

    const int t    = threadIdx.x;
    const int bid  = blockIdx.x;
    const int g    = (bid & 7) + 8 * ((bid >> 3) & 3);
    const int qt   = bid >> 5;
    const int b    = g >> 3;
    const int ct   = g & 7;

    const int lane = t & 63;
    const int wv   = t >> 6;
    const int quad = lane >> 4;
    const int l15  = lane & 15;

    const int qrow0 = b * NQ + qt * QT;
    const int cbase = ct * CT;

    float4 qv = qp[qrow0 + wv * 16 + l15];
    const float qx = qv.x, qy = qv.y, qz = qv.z, qw = qv.w;

    const int rp  = (t & 7) + 8 * wv;
    const int c4l = (t >> 3) & 7;

    const float*  vb   = v + (size_t)b * NF * CC + cbase;
    const float4* kp4g = (const float4*)(kp3 + (size_t)b * NF * 3);

    floatx4 acc[6];
#pragma unroll
    for (int cs = 0; cs < 6; ++cs) acc[cs] = (floatx4){0.f, 0.f, 0.f, 0.f};

    float va0[3][4], va1[3][4];
    float4 kpld = make_float4(0.f, 0.f, 0.f, 0.f);

#pragma unroll
    for (int rep = 0; rep < 3; ++rep) {
        int col = 4 * (c4l + 8 * rep);
        const float4* p0 = (const float4*)(vb + (size_t)(2 * rp) * CC + col);
        float4 a = p0[0];
        float4 bq = p0[CC / 4];
        va0[rep][0] = a.x;  va0[rep][1] = a.y;  va0[rep][2] = a.z;  va0[rep][3] = a.w;
        va1[rep][0] = bq.x; va1[rep][1] = bq.y; va1[rep][2] = bq.z; va1[rep][3] = bq.w;
    }
    if (t < 96) kpld = kp4g[t];

    for (int ch = 0; ch < NCH; ++ch) {
        const int p = ch & 1;
#pragma unroll
        for (int rep = 0; rep < 3; ++rep) {
            int c0 = 4 * (c4l + 8 * rep);
#pragma unroll
            for (int w = 0; w < 4; ++w) {
                unsigned int pk = f2bf(va0[rep][w]) | (f2bf(va1[rep][w]) << 16);
                vTd[p][(c0 + w) * 68 + (rp ^ (4 * c4l))] = pk;
            }
        }
        if (t < 96) kplB[p][t] = kpld;
        __syncthreads();

        if (ch + 1 < NCH) {
            int m0 = (ch + 1) * BK;
#pragma unroll
            for (int rep = 0; rep < 3; ++rep) {
                int col = 4 * (c4l + 8 * rep);
                const float4* p0 = (const float4*)(vb + (size_t)(m0 + 2 * rp) * CC + col);
                float4 a = p0[0];
                float4 bq = p0[CC / 4];
                va0[rep][0] = a.x;  va0[rep][1] = a.y;  va0[rep][2] = a.z;  va0[rep][3] = a.w;
                va1[rep][0] = bq.x; va1[rep][1] = bq.y; va1[rep][2] = bq.z; va1[rep][3] = bq.w;
            }
            if (t < 96) kpld = kp4g[(ch + 1) * 96 + t];
        }

#pragma unroll
        for (int kk = 0; kk < BK; kk += 32) {
            union { float4 v4[6]; float f[24]; } kq;
            const int kb4 = (kk * 3) / 4 + 6 * quad;
#pragma unroll
            for (int i = 0; i < 6; ++i) kq.v4[i] = kplB[p][kb4 + i];

            union { short8 s; unsigned int d[4]; } af;
#pragma unroll
            for (int j = 0; j < 8; j += 2) {
                float s0 = fmaf(qx, kq.f[3 * j],
                           fmaf(qy, kq.f[3 * j + 1],
                           fmaf(qz, kq.f[3 * j + 2], qw)));
                float s1 = fmaf(qx, kq.f[3 * j + 3],
                           fmaf(qy, kq.f[3 * j + 4],
                           fmaf(qz, kq.f[3 * j + 5], qw)));
                af.d[j >> 1] = f2bf(EXP2F(s0)) | (f2bf(EXP2F(s1)) << 16);
            }

#pragma unroll
            for (int cs = 0; cs < 6; ++cs) {
                int c  = cs * 16 + l15;
                int d0 = ((kk >> 1) + 4 * quad) ^ (4 * ((c >> 2) & 7));
                union { uint4 u; short8 s; } bw;
                bw.u = *(const uint4*)&vTd[p][c * 68 + d0];
                acc[cs] = __builtin_amdgcn_mfma_f32_16x16x32_bf16(
                    af.s, bw.s, acc[cs], 0, 0, 0);
            }
        }
        __syncthreads();
    }

#pragma unroll
    for (int vv = 0; vv < 4; ++vv) {
        int row = qrow0 + wv * 16 + quad * 4 + vv;
        float lv = rstat[row].y;
        float* orow = out + (size_t)row * CC + cbase + l15;
#pragma unroll
        for (int cs = 0; cs < 6; ++cs)
            orow[cs * 16] = acc[cs][vv] * lv;
    }
}

// ---------------------------------------------------------------------------
extern "C" void kernel_launch(void* const* d_in, const int* in_sizes, int n_in,
                              void* d_out, int out_size, void* d_ws, size_t ws_size,
                              hipStream_t stream) {
    const float* q  = (const float*)d_in[0];
    const float* k  = (const float*)d_in[1];
    const float* v  = (const float*)d_in[2];
    const float* W1 = (const float*)d_in[3];
    const float* b1 = (const float*)d_in[4];
    const float* W2 = (const float*)d_in[5];
    const float* b2 = (const float*)d_in[6];
    float* out = (float*)d_out;

    // ws layout: kp3 (768K) | qp (128K) | rstat (64K) | vpk (96M) | partials (72M)
    float*  kp3   = (float*)d_ws;
    float4* qpW   = (float4*)((char*)d_ws + (size_t)Bt * NF * 3 * 4);
    float2* rstat = (float2*)((char*)d_ws + (size_t)Bt * NF * 3 * 4 + (size_t)Bt * NQ * 16);
    char*   vpk   = (char*)d_ws + 983040;
    float*  part  = (float*)((char*)d_ws + 983040 + (size_t)NTILE * TILEB);
    const size_t need = 983040 + (size_t)NTILE * TILEB
                      + (size_t)3 * Bt * NQ * CC * 4;   // ~177.1 MB

    hipLaunchKernelGGL(prep_kernel, dim3((Bt * NQ + Bt * NF) / 256), dim3(256), 0, stream,
                       q, k, W1, b1, W2, b2, qpW, kp3);
    hipLaunchKernelGGL(stats_kernel, dim3(Bt * (NQ / 16)), dim3(256), 0, stream,
                       qpW, kp3, rstat);

    if (ws_size >= need) {
        hipLaunchKernelGGL(prep_v_kernel, dim3(Bt * 512 * 12), dim3(256), 0, stream,
                           v, vpk);
        hipLaunchKernelGGL(attn_main32_kernel, dim3(256), dim3(512), 0, stream,
                           vpk, qpW, kp3, out, part);
        hipLaunchKernelGGL(reduce_kernel, dim3(2048), dim3(256), 0, stream,
                           out, part, rstat);
    } else {
        // workspace too small for prepack+partials: proven fallback path
        hipLaunchKernelGGL(attn_mfma_kernel, dim3(Bt * (NQ / QT) * (CC / CT)), dim3(THR), 0, stream,
                           v, qpW, kp3, rstat, out);
    }
}